// Round 18
// baseline (263.211 us; speedup 1.0000x reference)
//
#include <hip/hip_runtime.h>

#define DEV __device__ __forceinline__

typedef short bh8 __attribute__((ext_vector_type(8)));
typedef short bh4 __attribute__((ext_vector_type(4)));
typedef float fx4 __attribute__((ext_vector_type(4)));

// ---- constants ----
#define T_ 512
#define B_ 8
#define E_ 1024
#define H_ 32
#define DH_ 32
#define S_ 768
#define NEXP_ 256
#define SCALING_ 0.17677669529663687f
// ws offsets (bytes)
#define OFF_QB    ((size_t)0)
#define OFF_WB    ((size_t)8388608)
#define OFF_QRM   ((size_t)16777216)
#define OFF_KRM   ((size_t)25165824)
#define OFF_VRM   ((size_t)33554432)
#define OFF_KBF   ((size_t)41943040)
#define OFF_VT    ((size_t)54525952)
#define OFF_ATTN  ((size_t)67108864)
#define OFF_XHAT  ((size_t)75497472)
#define OFF_MASK  ((size_t)83886080)
#define OFF_FLAG  ((size_t)83910656)
#define OFF_MEANP ((size_t)100663296)   // 2 slabs of [B][T][S] f32
#define SLAB_ ((size_t)B_ * T_ * S_)    // 3145728 elems

// LDS-only barrier: keeps global loads in flight (no vmcnt drain).
#define BARRIER_LGKM() do { \
  asm volatile("s_waitcnt lgkmcnt(0)" ::: "memory"); \
  __builtin_amdgcn_s_barrier(); \
} while (0)

DEV float bf2f(short u) {
  union { unsigned int i; float f; } x;
  x.i = ((unsigned int)(unsigned short)u) << 16;
  return x.f;
}
DEV short f2bf(float f) {
  union { float f; unsigned int u; } x; x.f = f;
  unsigned int r = x.u + 0x7fffu + ((x.u >> 16) & 1u);
  return (short)(r >> 16);
}
DEV void gl_lds16(const void* g, void* l) {
  __builtin_amdgcn_global_load_lds(
      (const __attribute__((address_space(1))) unsigned int*)g,
      (__attribute__((address_space(3))) unsigned int*)l, 16, 0, 0);
}

// ---- convert f32 -> bf16: query + 4 weights; block 0 also detects bool width ----
__global__ __launch_bounds__(256) void conv_all(
    const float* __restrict__ q, const float* __restrict__ wq,
    const float* __restrict__ wk, const float* __restrict__ wv,
    const float* __restrict__ wo, short* __restrict__ QB, short* __restrict__ WB,
    const unsigned char* __restrict__ em, int* __restrict__ flag) {
  if (blockIdx.x == 0) {
    __shared__ int f;
    if (threadIdx.x == 0) f = 0;
    __syncthreads();
    for (int i = threadIdx.x; i < 2048; i += 256)
      if ((i & 3) && em[i]) atomicOr(&f, 1);
    __syncthreads();
    if (threadIdx.x == 0) *flag = f;   // 1 => bool stored as 1 byte
  }
  size_t i4 = ((size_t)blockIdx.x * 256 + threadIdx.x) * 4;
  const float* s; short* d;
  if (i4 < (size_t)4194304) { s = q + i4; d = QB + i4; }
  else {
    size_t r = i4 - 4194304; int m = (int)(r >> 20); size_t o = r & 1048575;
    const float* ws4[4] = {wq, wk, wv, wo};
    s = ws4[m] + o; d = WB + ((size_t)m << 20) + o;
  }
  fx4 v = *(const fx4*)s;
  bh4 p = { f2bf(v[0]), f2bf(v[1]), f2bf(v[2]), f2bf(v[3]) };
  *(bh4*)d = p;
}

// ---- fused QKV GEMM ----
__global__ __launch_bounds__(256) void qkv_gemm(
    const short* __restrict__ QB, const short* __restrict__ WB,
    const float* __restrict__ bq, const float* __restrict__ bv,
    short* __restrict__ q_rm, short* __restrict__ k_rm, short* __restrict__ v_rm) {
  __shared__ __align__(16) short As[128 * 32];
  __shared__ __align__(16) short Ws[128 * 32];
  const int tid = threadIdx.x;
  const int mt = blockIdx.x, nt = blockIdx.y;
  const int mat = nt >> 3;
  const size_t m0 = (size_t)mt * 128;
  const int n0 = (nt & 7) << 7;
  const short* W = WB + (size_t)mat * (1024 * 1024);
  const int l = tid & 63, wv_ = tid >> 6;
  const int lt = l & 15, g = l >> 4;
  const int wm = wv_ >> 1, wn = wv_ & 1;
  fx4 acc[4][4];
#pragma unroll
  for (int i = 0; i < 4; ++i)
#pragma unroll
    for (int j = 0; j < 4; ++j) acc[i][j] = fx4{0.f, 0.f, 0.f, 0.f};

  const int r0 = tid >> 2, c0 = tid & 3;
  for (int kt = 0; kt < 32; ++kt) {
    const int k0 = kt * 32;
    __syncthreads();
    gl_lds16(QB + (m0 + r0) * 1024 + k0 + c0 * 8,        As + r0 * 32 + c0 * 8);
    gl_lds16(QB + (m0 + 64 + r0) * 1024 + k0 + c0 * 8,   As + (64 + r0) * 32 + c0 * 8);
    gl_lds16(W + (size_t)(n0 + r0) * 1024 + k0 + c0 * 8,      Ws + r0 * 32 + c0 * 8);
    gl_lds16(W + (size_t)(n0 + 64 + r0) * 1024 + k0 + c0 * 8, Ws + (64 + r0) * 32 + c0 * 8);
    __syncthreads();
    bh8 af[4], wf[4];
#pragma unroll
    for (int i = 0; i < 4; ++i) af[i] = *(const bh8*)(As + (wm * 64 + i * 16 + lt) * 32 + g * 8);
#pragma unroll
    for (int j = 0; j < 4; ++j) wf[j] = *(const bh8*)(Ws + (wn * 64 + j * 16 + lt) * 32 + g * 8);
#pragma unroll
    for (int i = 0; i < 4; ++i)
#pragma unroll
      for (int j = 0; j < 4; ++j)
        acc[i][j] = __builtin_amdgcn_mfma_f32_16x16x32_bf16(af[i], wf[j], acc[i][j], 0, 0, 0);
  }
  short* outp = (mat == 0) ? q_rm : (mat == 1) ? k_rm : v_rm;
#pragma unroll
  for (int i = 0; i < 4; ++i) {
    const size_t rowb = m0 + wm * 64 + i * 16 + g * 4;
#pragma unroll
    for (int j = 0; j < 4; ++j) {
      const int col = n0 + wn * 64 + j * 16 + lt;
      const float bias = (mat == 0) ? bq[col] : (mat == 2) ? bv[col] : 0.0f;
#pragma unroll
      for (int jj = 0; jj < 4; ++jj) {
        float v = acc[i][j][jj] + bias;
        if (mat == 0) v *= SCALING_;
        outp[(rowb + jj) * 1024 + col] = f2bf(v);
      }
    }
  }
}

// ---- repack v2: fatter blocks (4 K-units / 2 V-chunks each) ----
__global__ __launch_bounds__(256) void repack(
    const short* __restrict__ k_rm, const short* __restrict__ v_rm,
    const int* __restrict__ oc, const unsigned char* __restrict__ em,
    const unsigned char* __restrict__ kp, const int* __restrict__ flag,
    short* __restrict__ kbf, short* __restrict__ vT, float* __restrict__ maskval) {
  __shared__ __align__(16) short lv[2][64 * 40];
  const int bid = blockIdx.x, tid = threadIdx.x;
  if (bid < 768) {
#pragma unroll
    for (int k = 0; k < 4; ++k) {
      int u = bid * 1024 + k * 256 + tid;
      int d8 = u & 3;
      int s = (u >> 2) % 768;
      int hb = (u >> 2) / 768;
      int b = hb >> 5, h = hb & 31;
      int srct = (s < 512) ? s : (oc[b * 256 + (s - 512)] + 1);
      bh8 val = *(const bh8*)(k_rm + ((size_t)srct * 8 + b) * 1024 + h * 32 + d8 * 8);
      *(bh8*)(kbf + ((size_t)hb * 768 + s) * 32 + d8 * 8) = val;
    }
  } else if (bid < 2304) {
    int idx2 = bid - 768;
    int s_loc = tid >> 2, d8 = tid & 3;
#pragma unroll
    for (int k = 0; k < 2; ++k) {
      int chunk = idx2 * 2 + k;
      int c = chunk % 12, hb = chunk / 12;
      int b = hb >> 5, h = hb & 31;
      int s = c * 64 + s_loc;
      int srct = (s < 512) ? s : (oc[b * 256 + (s - 512)] + 1);
      bh8 val = *(const bh8*)(v_rm + ((size_t)srct * 8 + b) * 1024 + h * 32 + d8 * 8);
      *(bh8*)(lv[k] + s_loc * 40 + d8 * 8) = val;
    }
    __syncthreads();
    int d = tid >> 3, sj = tid & 7;
#pragma unroll
    for (int k = 0; k < 2; ++k) {
      int chunk = idx2 * 2 + k;
      int c = chunk % 12, hb = chunk / 12;
      bh8 o;
#pragma unroll
      for (int e = 0; e < 8; ++e) o[e] = lv[k][(sj * 8 + e) * 40 + d];
      *(bh8*)(vT + ((size_t)hb * 32 + d) * 768 + c * 64 + sj * 8) = o;
    }
  } else {
    int u = (bid - 2304) * 256 + tid;
    if (u < 6144) {
      int s = u % 768, b = u / 768;
      int m;
      if (*flag) {
        m = (s < 512) ? (int)kp[b * 512 + s] : (int)em[b * 256 + (s - 512)];
      } else {
        const int* kpi = (const int*)kp; const int* emi = (const int*)em;
        m = (s < 512) ? kpi[b * 512 + s] : emi[b * 256 + (s - 512)];
      }
      maskval[u] = m ? -3.0e38f : 0.0f;
    }
  }
}

// ---- attention v17: WAVE-LOCAL bias staging. bias_lds is per-wave column
//      blocks [4][16][192]; wave w stages & reads ONLY block w, so the stage
//      needs a wave-local vmcnt wait only -- no WG-wide vmcnt drain ever.
//      Stage for head h+1 issues right after head h's score reads complete;
//      denominator barrier + PV + reduce (~1us) cover its latency. First 3
//      PV V-chunks are hoisted to regs before the stage (in-order vmcnt).
//      3 lgkm-only barriers/head; 8 independent fetch streams per CU. ----
__global__ __launch_bounds__(256) void attn_kernel(
    const short* __restrict__ q_rm, const short* __restrict__ kbf,
    const short* __restrict__ vT, const float* __restrict__ bias,
    const float* __restrict__ maskval, short* __restrict__ attn_bf,
    float* __restrict__ mean_part) {
  __shared__ __align__(16) float bias_lds[4][16][192];  // 48 KB, per-wave blocks
  __shared__ __align__(16) short p_st[4 * 16 * 40];     // 5 KB
  __shared__ float lpart[4][16];                        // 256 B
  __shared__ __align__(16) float attred[4 * 64 * 8];    // 8 KB
  __shared__ __align__(16) float maskv[768];            // 3 KB

  const int tid = threadIdx.x, blk = blockIdx.x;
  const int group = blk & 15, tt = blk >> 4;            // XCD = group&7
  const int hg = group & 1, b = group >> 1;
  const int t0 = tt * 16;
  const int w = tid >> 6, l = tid & 63, lt = l & 15, g = l >> 4;
  const int sbase = w * 192;

  for (int u = tid; u < 768; u += 256) maskv[u] = maskval[b * 768 + u];

  const float* bias_base = bias + ((size_t)(b * 32) * 512 + t0) * 768;
  // wave-local stage of own column block [16t][192s] for head hh_:
  // gidx = rr*64 + l; row = gidx/48, grp = gidx%48; LDS dst linear in l.
#define STAGE_OWN(hh_) do { \
    const float* hb_ = bias_base + (size_t)(hh_) * 512 * 768; \
    _Pragma("unroll") \
    for (int rr = 0; rr < 12; ++rr) { \
      int gidx = rr * 64 + l; \
      int row_ = gidx / 48, grp_ = gidx - row_ * 48; \
      gl_lds16(hb_ + (size_t)row_ * 768 + sbase + grp_ * 4, \
               (char*)bias_lds + (size_t)w * 12288 + (size_t)gidx * 16); \
    } \
  } while (0)

  STAGE_OWN(hg * 16);
  asm volatile("s_waitcnt vmcnt(0) lgkmcnt(0)" ::: "memory");
  __builtin_amdgcn_s_barrier();   // publish maskv (bias block is wave-private)

  const fx4 zf = {0.f, 0.f, 0.f, 0.f};
  float msum[48];
#pragma unroll
  for (int i = 0; i < 48; ++i) msum[i] = 0.f;

  const float* blkb = &bias_lds[w][0][0];

  for (int i = 0; i < 16; ++i) {
    const int hh = hg * 16 + i;
    const int bh = b * 32 + hh;

    // wave-local: own stage (issued during previous head) has landed
    asm volatile("s_waitcnt vmcnt(0)" ::: "memory");

    const bh8 qf = *(const bh8*)(q_rm + ((size_t)(t0 + lt) * 8 + b) * 1024 + hh * 32 + g * 8);
    const short* kp_ = kbf + (size_t)bh * 768 * 32;

    // ---- score pass: C[t][s]; bias from OWN LDS block (stride 192) ----
    unsigned exu[24];
    float ls0 = 0.f, ls1 = 0.f, ls2 = 0.f, ls3 = 0.f;
#pragma unroll
    for (int c = 0; c < 12; ++c) {
      const int s0 = sbase + c * 16;
      bh8 kf = *(const bh8*)(kp_ + (s0 + lt) * 32 + g * 8);
      fx4 sc = __builtin_amdgcn_mfma_f32_16x16x32_bf16(qf, kf, zf, 0, 0, 0);
      const float mv = maskv[s0 + lt];
      const float* bl = blkb + (g * 4) * 192 + c * 16 + lt;
      float e0 = __expf(sc[0] + bl[0]       + mv);
      float e1 = __expf(sc[1] + bl[192]     + mv);
      float e2 = __expf(sc[2] + bl[2 * 192] + mv);
      float e3 = __expf(sc[3] + bl[3 * 192] + mv);
      ls0 += e0; ls1 += e1; ls2 += e2; ls3 += e3;
      exu[c * 2]     = (unsigned)(unsigned short)f2bf(e0) | ((unsigned)(unsigned short)f2bf(e1) << 16);
      exu[c * 2 + 1] = (unsigned)(unsigned short)f2bf(e2) | ((unsigned)(unsigned short)f2bf(e3) << 16);
    }
    // own bias LDS reads complete before the block is overwritten
    asm volatile("s_waitcnt lgkmcnt(0)" ::: "memory");

    // ---- hoist first 3 PV V-chunks to regs BEFORE issuing the stage ----
    const short* vp0 = vT + ((size_t)bh * 32 + lt) * 768;
    const short* vp1 = vp0 + 16 * 768;
    bh8 vf[6];
#pragma unroll
    for (int c2 = 0; c2 < 3; ++c2) {
      vf[c2 * 2]     = *(const bh8*)(vp0 + sbase + c2 * 32 + g * 8);
      vf[c2 * 2 + 1] = *(const bh8*)(vp1 + sbase + c2 * 32 + g * 8);
    }
    // issue next head's stage into own block (latency covered by PV phase)
    if (i < 15) STAGE_OWN(hh + 1);

    // ---- denominator across waves ----
#pragma unroll
    for (int m = 1; m < 16; m <<= 1) {
      ls0 += __shfl_xor(ls0, m); ls1 += __shfl_xor(ls1, m);
      ls2 += __shfl_xor(ls2, m); ls3 += __shfl_xor(ls3, m);
    }
    if (lt == 0) {
      lpart[w][g * 4 + 0] = ls0; lpart[w][g * 4 + 1] = ls1;
      lpart[w][g * 4 + 2] = ls2; lpart[w][g * 4 + 3] = ls3;
    }
    BARRIER_LGKM();
    float linv[4];
#pragma unroll
    for (int jj = 0; jj < 4; ++jj)
      linv[jj] = 1.0f / (lpart[0][g * 4 + jj] + lpart[1][g * 4 + jj] +
                         lpart[2][g * 4 + jj] + lpart[3][g * 4 + jj]);
    const float linv_acc = 1.0f / (lpart[0][lt] + lpart[1][lt] + lpart[2][lt] + lpart[3][lt]);

    // ---- PV on unnormalized P (transpose via p_st) + mean accumulate ----
    fx4 acc0 = zf, acc1 = zf;
    short* pw_base = p_st + w * 640;
#pragma unroll
    for (int c2 = 0; c2 < 6; ++c2) {
      const int s0 = sbase + c2 * 32;
#pragma unroll
      for (int cc = 0; cc < 2; ++cc) {
        const int c = c2 * 2 + cc;
        unsigned u01 = exu[c * 2], u23 = exu[c * 2 + 1];
        short* pcol = pw_base + cc * 16 + lt;
        pcol[(g * 4 + 0) * 40] = (short)(u01 & 0xffffu);
        pcol[(g * 4 + 1) * 40] = (short)(u01 >> 16);
        pcol[(g * 4 + 2) * 40] = (short)(u23 & 0xffffu);
        pcol[(g * 4 + 3) * 40] = (short)(u23 >> 16);
        msum[c * 4 + 0] += bf2f((short)(u01 & 0xffffu)) * linv[0];
        msum[c * 4 + 1] += bf2f((short)(u01 >> 16)) * linv[1];
        msum[c * 4 + 2] += bf2f((short)(u23 & 0xffffu)) * linv[2];
        msum[c * 4 + 3] += bf2f((short)(u23 >> 16)) * linv[3];
      }
      bh8 pf = *(const bh8*)(pw_base + lt * 40 + g * 8);
      bh8 vf0 = (c2 < 3) ? vf[c2 * 2]     : *(const bh8*)(vp0 + s0 + g * 8);
      bh8 vf1 = (c2 < 3) ? vf[c2 * 2 + 1] : *(const bh8*)(vp1 + s0 + g * 8);
      acc0 = __builtin_amdgcn_mfma_f32_16x16x32_bf16(vf0, pf, acc0, 0, 0, 0);
      acc1 = __builtin_amdgcn_mfma_f32_16x16x32_bf16(vf1, pf, acc1, 0, 0, 0);
    }
#pragma unroll
    for (int jj = 0; jj < 4; ++jj) { acc0[jj] *= linv_acc; acc1[jj] *= linv_acc; }

    // ---- cross-wave reduce of attn^T, write output ----
    float* ar = attred + (w * 64 + l) * 8;
    *(fx4*)(ar) = acc0;
    *(fx4*)(ar + 4) = acc1;
    BARRIER_LGKM();
    if (w < 2) {
      float s0v = 0.f, s1v = 0.f, s2v = 0.f, s3v = 0.f;
#pragma unroll
      for (int w2 = 0; w2 < 4; ++w2) {
        const float* a2 = attred + (w2 * 64 + l) * 8 + w * 4;
        s0v += a2[0]; s1v += a2[1]; s2v += a2[2]; s3v += a2[3];
      }
      bh4 o = { f2bf(s0v), f2bf(s1v), f2bf(s2v), f2bf(s3v) };
      *(bh4*)(attn_bf + ((size_t)(t0 + lt) * 8 + b) * 1024 + hh * 32 + w * 16 + g * 4) = o;
    }
    BARRIER_LGKM();   // attred safe to reuse next head (lgkm-only)
  }

  // ---- head-mean partial writeout: private hg-slab, plain stores ----
  float* mob = mean_part + (size_t)hg * SLAB_ + ((size_t)b * 512 + t0) * 768;
#pragma unroll
  for (int c = 0; c < 12; ++c) {
    const int s = sbase + c * 16 + lt;
#pragma unroll
    for (int jj = 0; jj < 4; ++jj) {
      mob[(size_t)(g * 4 + jj) * 768 + s] = msum[c * 4 + jj] * 0.03125f;
    }
  }
#undef STAGE_OWN
}

// ---- fused: blocks [0,3072) sum 2 hg-slabs; blocks [3072,4096) LayerNorm ----
__global__ __launch_bounds__(256) void mean_ln(
    const float* __restrict__ mean_part, float* __restrict__ mean_out,
    const short* __restrict__ attn_bf, const float* __restrict__ lg,
    const float* __restrict__ lb, short* __restrict__ xhat) {
  if (blockIdx.x < 3072) {
    size_t i = ((size_t)blockIdx.x * 256 + threadIdx.x) * 4;
    fx4 a = *(const fx4*)(mean_part + i);
    fx4 b = *(const fx4*)(mean_part + SLAB_ + i);
#pragma unroll
    for (int k = 0; k < 4; ++k) a[k] = a[k] + b[k];
    *(fx4*)(mean_out + i) = a;
    return;
  }
  const int w = threadIdx.x >> 6, l = threadIdx.x & 63;
  const size_t row = (size_t)(blockIdx.x - 3072) * 4 + w;
  const short* x = attn_bf + row * 1024 + l * 16;
  bh8 a0 = *(const bh8*)x, a1 = *(const bh8*)(x + 8);
  float xs[16];
#pragma unroll
  for (int i = 0; i < 8; ++i) { xs[i] = bf2f(a0[i]); xs[8 + i] = bf2f(a1[i]); }
  float s1 = 0.f, s2 = 0.f;
#pragma unroll
  for (int i = 0; i < 16; ++i) { s1 += xs[i]; s2 += xs[i] * xs[i]; }
  for (int m = 1; m < 64; m <<= 1) { s1 += __shfl_xor(s1, m); s2 += __shfl_xor(s2, m); }
  const float mu = s1 * (1.0f / 1024.0f);
  float var = s2 * (1.0f / 1024.0f) - mu * mu;
  var = fmaxf(var, 0.f);
  const float rs = rsqrtf(var + 1e-5f);
  const float* lgp = lg + l * 16;
  const float* lbp = lb + l * 16;
  bh8 o0, o1;
#pragma unroll
  for (int i = 0; i < 8; ++i) {
    o0[i] = f2bf((xs[i] - mu) * rs * lgp[i] + lbp[i]);
    o1[i] = f2bf((xs[8 + i] - mu) * rs * lgp[8 + i] + lbp[8 + i]);
  }
  short* y = xhat + row * 1024 + l * 16;
  *(bh8*)y = o0;
  *(bh8*)(y + 8) = o1;
}

// ---- output projection GEMM ----
__global__ __launch_bounds__(256) void out_gemm(
    const short* __restrict__ XH, const short* __restrict__ WoB,
    const float* __restrict__ bo, float* __restrict__ out) {
  __shared__ __align__(16) short As[128 * 32];
  __shared__ __align__(16) short Ws[128 * 32];
  const int tid = threadIdx.x;
  const int mt = blockIdx.x, nt = blockIdx.y;
  const size_t m0 = (size_t)mt * 128;
  const int n0 = nt << 7;
  const int l = tid & 63, wv_ = tid >> 6;
  const int lt = l & 15, g = l >> 4;
  const int wm = wv_ >> 1, wn = wv_ & 1;
  fx4 acc[4][4];
#pragma unroll
  for (int i = 0; i < 4; ++i)
#pragma unroll
    for (int j = 0; j < 4; ++j) acc[i][j] = fx4{0.f, 0.f, 0.f, 0.f};
  const int r0 = tid >> 2, c0 = tid & 3;
  for (int kt = 0; kt < 32; ++kt) {
    const int k0 = kt * 32;
    __syncthreads();
    gl_lds16(XH + (m0 + r0) * 1024 + k0 + c0 * 8,        As + r0 * 32 + c0 * 8);
    gl_lds16(XH + (m0 + 64 + r0) * 1024 + k0 + c0 * 8,   As + (64 + r0) * 32 + c0 * 8);
    gl_lds16(WoB + (size_t)(n0 + r0) * 1024 + k0 + c0 * 8,      Ws + r0 * 32 + c0 * 8);
    gl_lds16(WoB + (size_t)(n0 + 64 + r0) * 1024 + k0 + c0 * 8, Ws + (64 + r0) * 32 + c0 * 8);
    __syncthreads();
    bh8 af[4], wf[4];
#pragma unroll
    for (int i = 0; i < 4; ++i) af[i] = *(const bh8*)(As + (wm * 64 + i * 16 + lt) * 32 + g * 8);
#pragma unroll
    for (int j = 0; j < 4; ++j) wf[j] = *(const bh8*)(Ws + (wn * 64 + j * 16 + lt) * 32 + g * 8);
#pragma unroll
    for (int i = 0; i < 4; ++i)
#pragma unroll
      for (int j = 0; j < 4; ++j)
        acc[i][j] = __builtin_amdgcn_mfma_f32_16x16x32_bf16(af[i], wf[j], acc[i][j], 0, 0, 0);
  }
#pragma unroll
  for (int i = 0; i < 4; ++i) {
    const size_t rowb = m0 + wm * 64 + i * 16 + g * 4;
#pragma unroll
    for (int j = 0; j < 4; ++j) {
      const int col = n0 + wn * 64 + j * 16 + lt;
      const float bb = bo[col];
#pragma unroll
      for (int jj = 0; jj < 4; ++jj)
        out[(rowb + jj) * 1024 + col] = acc[i][j][jj] + bb;
    }
  }
}

extern "C" void kernel_launch(void* const* d_in, const int* in_sizes, int n_in,
                              void* d_out, int out_size, void* d_ws, size_t ws_size,
                              hipStream_t stream) {
  const float* query = (const float*)d_in[0];
  const float* attn_bias = (const float*)d_in[1];
  const int* oc = (const int*)d_in[2];
  const unsigned char* em = (const unsigned char*)d_in[3];
  const unsigned char* kp = (const unsigned char*)d_in[4];
  const float* Wq = (const float*)d_in[5];
  const float* bq = (const float*)d_in[6];
  const float* Wk = (const float*)d_in[7];
  const float* Wv = (const float*)d_in[8];
  const float* bv = (const float*)d_in[9];
  const float* Wo = (const float*)d_in[10];
  const float* bo = (const float*)d_in[11];
  const float* lg = (const float*)d_in[12];
  const float* lb = (const float*)d_in[13];

  char* w = (char*)d_ws;
  short* QB    = (short*)(w + OFF_QB);
  short* WB    = (short*)(w + OFF_WB);
  short* QRM   = (short*)(w + OFF_QRM);
  short* KRM   = (short*)(w + OFF_KRM);
  short* VRM   = (short*)(w + OFF_VRM);
  short* KBF   = (short*)(w + OFF_KBF);
  short* VT    = (short*)(w + OFF_VT);
  short* ATTN  = (short*)(w + OFF_ATTN);
  short* XHAT  = (short*)(w + OFF_XHAT);
  float* MASK  = (float*)(w + OFF_MASK);
  int*   FLAG  = (int*)(w + OFF_FLAG);
  float* MEANP = (float*)(w + OFF_MEANP);

  float* out0 = (float*)d_out;                       // [T,B,E]
  float* mean_out = out0 + (size_t)T_ * B_ * E_;     // [B,T,S]

  conv_all<<<8192, 256, 0, stream>>>(query, Wq, Wk, Wv, Wo, QB, WB, em, FLAG);
  qkv_gemm<<<dim3(32, 24), 256, 0, stream>>>(QB, WB, bq, bv, QRM, KRM, VRM);
  repack<<<2328, 256, 0, stream>>>(KRM, VRM, oc, em, kp, FLAG, KBF, VT, MASK);
  attn_kernel<<<512, 256, 0, stream>>>(QRM, KBF, VT, attn_bias, MASK, ATTN, MEANP);
  mean_ln<<<4096, 256, 0, stream>>>(MEANP, mean_out, ATTN, lg, lb, XHAT);
  out_gemm<<<dim3(32, 8), 256, 0, stream>>>(XHAT, WB + (size_t)3 * 1024 * 1024, bo, out0);
}

// Round 19
// 240.323 us; speedup vs baseline: 1.0952x; 1.0952x over previous
//
#include <hip/hip_runtime.h>

#define DEV __device__ __forceinline__

typedef short bh8 __attribute__((ext_vector_type(8)));
typedef short bh4 __attribute__((ext_vector_type(4)));
typedef float fx4 __attribute__((ext_vector_type(4)));

// ---- constants ----
#define T_ 512
#define B_ 8
#define E_ 1024
#define H_ 32
#define DH_ 32
#define S_ 768
#define NEXP_ 256
#define SCALING_ 0.17677669529663687f
// ws offsets (bytes)
#define OFF_QB    ((size_t)0)
#define OFF_WB    ((size_t)8388608)
#define OFF_QRM   ((size_t)16777216)
#define OFF_KRM   ((size_t)25165824)
#define OFF_VRM   ((size_t)33554432)
#define OFF_KBF   ((size_t)41943040)
#define OFF_VT    ((size_t)54525952)
#define OFF_ATTN  ((size_t)67108864)
#define OFF_XHAT  ((size_t)75497472)
#define OFF_MASK  ((size_t)83886080)
#define OFF_FLAG  ((size_t)83910656)
#define OFF_MEANP ((size_t)100663296)   // 2 slabs of [B][T][S] f32
#define SLAB_ ((size_t)B_ * T_ * S_)    // 3145728 elems

// LDS-only barrier: keeps global loads in flight (no vmcnt drain).
#define BARRIER_LGKM() do { \
  asm volatile("s_waitcnt lgkmcnt(0)" ::: "memory"); \
  __builtin_amdgcn_s_barrier(); \
} while (0)

#define WAIT_VM0_BARRIER() do { \
  asm volatile("s_waitcnt vmcnt(0) lgkmcnt(0)" ::: "memory"); \
  __builtin_amdgcn_s_barrier(); \
} while (0)

DEV float bf2f(short u) {
  union { unsigned int i; float f; } x;
  x.i = ((unsigned int)(unsigned short)u) << 16;
  return x.f;
}
DEV short f2bf(float f) {
  union { float f; unsigned int u; } x; x.f = f;
  unsigned int r = x.u + 0x7fffu + ((x.u >> 16) & 1u);
  return (short)(r >> 16);
}
DEV void gl_lds16(const void* g, void* l) {
  __builtin_amdgcn_global_load_lds(
      (const __attribute__((address_space(1))) unsigned int*)g,
      (__attribute__((address_space(3))) unsigned int*)l, 16, 0, 0);
}

// ---- convert f32 -> bf16: query + 4 weights; block 0 also detects bool width ----
__global__ __launch_bounds__(256) void conv_all(
    const float* __restrict__ q, const float* __restrict__ wq,
    const float* __restrict__ wk, const float* __restrict__ wv,
    const float* __restrict__ wo, short* __restrict__ QB, short* __restrict__ WB,
    const unsigned char* __restrict__ em, int* __restrict__ flag) {
  if (blockIdx.x == 0) {
    __shared__ int f;
    if (threadIdx.x == 0) f = 0;
    __syncthreads();
    for (int i = threadIdx.x; i < 2048; i += 256)
      if ((i & 3) && em[i]) atomicOr(&f, 1);
    __syncthreads();
    if (threadIdx.x == 0) *flag = f;   // 1 => bool stored as 1 byte
  }
  size_t i4 = ((size_t)blockIdx.x * 256 + threadIdx.x) * 4;
  const float* s; short* d;
  if (i4 < (size_t)4194304) { s = q + i4; d = QB + i4; }
  else {
    size_t r = i4 - 4194304; int m = (int)(r >> 20); size_t o = r & 1048575;
    const float* ws4[4] = {wq, wk, wv, wo};
    s = ws4[m] + o; d = WB + ((size_t)m << 20) + o;
  }
  fx4 v = *(const fx4*)s;
  bh4 p = { f2bf(v[0]), f2bf(v[1]), f2bf(v[2]), f2bf(v[3]) };
  *(bh4*)d = p;
}

// ---- fused QKV GEMM ----
__global__ __launch_bounds__(256) void qkv_gemm(
    const short* __restrict__ QB, const short* __restrict__ WB,
    const float* __restrict__ bq, const float* __restrict__ bv,
    short* __restrict__ q_rm, short* __restrict__ k_rm, short* __restrict__ v_rm) {
  __shared__ __align__(16) short As[128 * 32];
  __shared__ __align__(16) short Ws[128 * 32];
  const int tid = threadIdx.x;
  const int mt = blockIdx.x, nt = blockIdx.y;
  const int mat = nt >> 3;
  const size_t m0 = (size_t)mt * 128;
  const int n0 = (nt & 7) << 7;
  const short* W = WB + (size_t)mat * (1024 * 1024);
  const int l = tid & 63, wv_ = tid >> 6;
  const int lt = l & 15, g = l >> 4;
  const int wm = wv_ >> 1, wn = wv_ & 1;
  fx4 acc[4][4];
#pragma unroll
  for (int i = 0; i < 4; ++i)
#pragma unroll
    for (int j = 0; j < 4; ++j) acc[i][j] = fx4{0.f, 0.f, 0.f, 0.f};

  const int r0 = tid >> 2, c0 = tid & 3;
  for (int kt = 0; kt < 32; ++kt) {
    const int k0 = kt * 32;
    __syncthreads();
    gl_lds16(QB + (m0 + r0) * 1024 + k0 + c0 * 8,        As + r0 * 32 + c0 * 8);
    gl_lds16(QB + (m0 + 64 + r0) * 1024 + k0 + c0 * 8,   As + (64 + r0) * 32 + c0 * 8);
    gl_lds16(W + (size_t)(n0 + r0) * 1024 + k0 + c0 * 8,      Ws + r0 * 32 + c0 * 8);
    gl_lds16(W + (size_t)(n0 + 64 + r0) * 1024 + k0 + c0 * 8, Ws + (64 + r0) * 32 + c0 * 8);
    __syncthreads();
    bh8 af[4], wf[4];
#pragma unroll
    for (int i = 0; i < 4; ++i) af[i] = *(const bh8*)(As + (wm * 64 + i * 16 + lt) * 32 + g * 8);
#pragma unroll
    for (int j = 0; j < 4; ++j) wf[j] = *(const bh8*)(Ws + (wn * 64 + j * 16 + lt) * 32 + g * 8);
#pragma unroll
    for (int i = 0; i < 4; ++i)
#pragma unroll
      for (int j = 0; j < 4; ++j)
        acc[i][j] = __builtin_amdgcn_mfma_f32_16x16x32_bf16(af[i], wf[j], acc[i][j], 0, 0, 0);
  }
  short* outp = (mat == 0) ? q_rm : (mat == 1) ? k_rm : v_rm;
#pragma unroll
  for (int i = 0; i < 4; ++i) {
    const size_t rowb = m0 + wm * 64 + i * 16 + g * 4;
#pragma unroll
    for (int j = 0; j < 4; ++j) {
      const int col = n0 + wn * 64 + j * 16 + lt;
      const float bias = (mat == 0) ? bq[col] : (mat == 2) ? bv[col] : 0.0f;
#pragma unroll
      for (int jj = 0; jj < 4; ++jj) {
        float v = acc[i][j][jj] + bias;
        if (mat == 0) v *= SCALING_;
        outp[(rowb + jj) * 1024 + col] = f2bf(v);
      }
    }
  }
}

// ---- repack v2: fatter blocks (4 K-units / 2 V-chunks each) ----
__global__ __launch_bounds__(256) void repack(
    const short* __restrict__ k_rm, const short* __restrict__ v_rm,
    const int* __restrict__ oc, const unsigned char* __restrict__ em,
    const unsigned char* __restrict__ kp, const int* __restrict__ flag,
    short* __restrict__ kbf, short* __restrict__ vT, float* __restrict__ maskval) {
  __shared__ __align__(16) short lv[2][64 * 40];
  const int bid = blockIdx.x, tid = threadIdx.x;
  if (bid < 768) {
#pragma unroll
    for (int k = 0; k < 4; ++k) {
      int u = bid * 1024 + k * 256 + tid;
      int d8 = u & 3;
      int s = (u >> 2) % 768;
      int hb = (u >> 2) / 768;
      int b = hb >> 5, h = hb & 31;
      int srct = (s < 512) ? s : (oc[b * 256 + (s - 512)] + 1);
      bh8 val = *(const bh8*)(k_rm + ((size_t)srct * 8 + b) * 1024 + h * 32 + d8 * 8);
      *(bh8*)(kbf + ((size_t)hb * 768 + s) * 32 + d8 * 8) = val;
    }
  } else if (bid < 2304) {
    int idx2 = bid - 768;
    int s_loc = tid >> 2, d8 = tid & 3;
#pragma unroll
    for (int k = 0; k < 2; ++k) {
      int chunk = idx2 * 2 + k;
      int c = chunk % 12, hb = chunk / 12;
      int b = hb >> 5, h = hb & 31;
      int s = c * 64 + s_loc;
      int srct = (s < 512) ? s : (oc[b * 256 + (s - 512)] + 1);
      bh8 val = *(const bh8*)(v_rm + ((size_t)srct * 8 + b) * 1024 + h * 32 + d8 * 8);
      *(bh8*)(lv[k] + s_loc * 40 + d8 * 8) = val;
    }
    __syncthreads();
    int d = tid >> 3, sj = tid & 7;
#pragma unroll
    for (int k = 0; k < 2; ++k) {
      int chunk = idx2 * 2 + k;
      int c = chunk % 12, hb = chunk / 12;
      bh8 o;
#pragma unroll
      for (int e = 0; e < 8; ++e) o[e] = lv[k][(sj * 8 + e) * 40 + d];
      *(bh8*)(vT + ((size_t)hb * 32 + d) * 768 + c * 64 + sj * 8) = o;
    }
  } else {
    int u = (bid - 2304) * 256 + tid;
    if (u < 6144) {
      int s = u % 768, b = u / 768;
      int m;
      if (*flag) {
        m = (s < 512) ? (int)kp[b * 512 + s] : (int)em[b * 256 + (s - 512)];
      } else {
        const int* kpi = (const int*)kp; const int* emi = (const int*)em;
        m = (s < 512) ? kpi[b * 512 + s] : emi[b * 256 + (s - 512)];
      }
      maskval[u] = m ? -3.0e38f : 0.0f;
    }
  }
}

// ---- attention (R14 configuration, measured best 240.8us):
//      2 WGs/CU TLP; 256 thr / 4 waves; grid 512 = (b, tt, hg); 16 heads/WG;
//      single-buffered 48KB bias stage per head (stage -> vmcnt0 -> compute);
//      co-resident WG overlaps fetch with compute via HW wave scheduling. ----
__global__ __launch_bounds__(256) void attn_kernel(
    const short* __restrict__ q_rm, const short* __restrict__ kbf,
    const short* __restrict__ vT, const float* __restrict__ bias,
    const float* __restrict__ maskval, short* __restrict__ attn_bf,
    float* __restrict__ mean_part) {
  __shared__ __align__(16) float bias_lds[16 * 768];   // 48 KB
  __shared__ __align__(16) short p_st[4 * 16 * 40];    // 5 KB
  __shared__ float lpart[4][16];                       // 256 B
  __shared__ __align__(16) float attred[4 * 64 * 8];   // 8 KB
  __shared__ __align__(16) float maskv[768];           // 3 KB

  const int tid = threadIdx.x, blk = blockIdx.x;
  const int hg = blk & 1, tt = (blk >> 1) & 31, b = blk >> 6;
  const int t0 = tt * 16;
  const int w = tid >> 6, l = tid & 63, lt = l & 15, g = l >> 4;
  const int sbase = w * 192;

  for (int u = tid; u < 768; u += 256) maskv[u] = maskval[b * 768 + u];
  BARRIER_LGKM();

  const float* bias_base = bias + ((size_t)(b * 32) * 512 + t0) * 768;
  const fx4 zf = {0.f, 0.f, 0.f, 0.f};
  float msum[48];
#pragma unroll
  for (int i = 0; i < 48; ++i) msum[i] = 0.f;

  for (int i = 0; i < 16; ++i) {
    const int hh = hg * 16 + i;
    const int bh = b * 32 + hh;

    // ---- stage this head's bias tile, drain, publish ----
    const float* hb_ = bias_base + (size_t)hh * 512 * 768;
#pragma unroll
    for (int r = 0; r < 12; ++r)
      gl_lds16(hb_ + (size_t)(r * 256 + tid) * 4,
               (char*)bias_lds + (size_t)(r * 256 + tid) * 16);
    WAIT_VM0_BARRIER();

    const bh8 qf = *(const bh8*)(q_rm + ((size_t)(t0 + lt) * 8 + b) * 1024 + hh * 32 + g * 8);
    const short* kp_ = kbf + (size_t)bh * 768 * 32;

    // ---- score pass: C[t][s]; wave covers 192 s-cols; bias from LDS ----
    unsigned exu[24];
    float ls0 = 0.f, ls1 = 0.f, ls2 = 0.f, ls3 = 0.f;
#pragma unroll
    for (int c = 0; c < 12; ++c) {
      const int s0 = sbase + c * 16;
      bh8 kf = *(const bh8*)(kp_ + (s0 + lt) * 32 + g * 8);
      fx4 sc = __builtin_amdgcn_mfma_f32_16x16x32_bf16(qf, kf, zf, 0, 0, 0);
      const float mv = maskv[s0 + lt];
      const float* bl = bias_lds + (g * 4) * 768 + s0 + lt;
      float e0 = __expf(sc[0] + bl[0]       + mv);
      float e1 = __expf(sc[1] + bl[768]     + mv);
      float e2 = __expf(sc[2] + bl[2 * 768] + mv);
      float e3 = __expf(sc[3] + bl[3 * 768] + mv);
      ls0 += e0; ls1 += e1; ls2 += e2; ls3 += e3;
      exu[c * 2]     = (unsigned)(unsigned short)f2bf(e0) | ((unsigned)(unsigned short)f2bf(e1) << 16);
      exu[c * 2 + 1] = (unsigned)(unsigned short)f2bf(e2) | ((unsigned)(unsigned short)f2bf(e3) << 16);
    }
#pragma unroll
    for (int m = 1; m < 16; m <<= 1) {
      ls0 += __shfl_xor(ls0, m); ls1 += __shfl_xor(ls1, m);
      ls2 += __shfl_xor(ls2, m); ls3 += __shfl_xor(ls3, m);
    }
    if (lt == 0) {
      lpart[w][g * 4 + 0] = ls0; lpart[w][g * 4 + 1] = ls1;
      lpart[w][g * 4 + 2] = ls2; lpart[w][g * 4 + 3] = ls3;
    }
    BARRIER_LGKM();   // lpart ready; all bias_lds reads complete
    float linv[4];
#pragma unroll
    for (int jj = 0; jj < 4; ++jj)
      linv[jj] = 1.0f / (lpart[0][g * 4 + jj] + lpart[1][g * 4 + jj] +
                         lpart[2][g * 4 + jj] + lpart[3][g * 4 + jj]);
    const float linv_acc = 1.0f / (lpart[0][lt] + lpart[1][lt] + lpart[2][lt] + lpart[3][lt]);

    // ---- PV on unnormalized P (transpose via p_st) + mean accumulate ----
    fx4 acc0 = zf, acc1 = zf;
    const short* vp0 = vT + ((size_t)bh * 32 + lt) * 768;
    const short* vp1 = vp0 + 16 * 768;
    short* pw_base = p_st + w * 640;
#pragma unroll
    for (int c2 = 0; c2 < 6; ++c2) {
      const int s0 = sbase + c2 * 32;
#pragma unroll
      for (int cc = 0; cc < 2; ++cc) {
        const int c = c2 * 2 + cc;
        unsigned u01 = exu[c * 2], u23 = exu[c * 2 + 1];
        short* pcol = pw_base + cc * 16 + lt;
        pcol[(g * 4 + 0) * 40] = (short)(u01 & 0xffffu);
        pcol[(g * 4 + 1) * 40] = (short)(u01 >> 16);
        pcol[(g * 4 + 2) * 40] = (short)(u23 & 0xffffu);
        pcol[(g * 4 + 3) * 40] = (short)(u23 >> 16);
        msum[c * 4 + 0] += bf2f((short)(u01 & 0xffffu)) * linv[0];
        msum[c * 4 + 1] += bf2f((short)(u01 >> 16)) * linv[1];
        msum[c * 4 + 2] += bf2f((short)(u23 & 0xffffu)) * linv[2];
        msum[c * 4 + 3] += bf2f((short)(u23 >> 16)) * linv[3];
      }
      bh8 pf = *(const bh8*)(pw_base + lt * 40 + g * 8);
      bh8 vf0 = *(const bh8*)(vp0 + s0 + g * 8);
      bh8 vf1 = *(const bh8*)(vp1 + s0 + g * 8);
      acc0 = __builtin_amdgcn_mfma_f32_16x16x32_bf16(vf0, pf, acc0, 0, 0, 0);
      acc1 = __builtin_amdgcn_mfma_f32_16x16x32_bf16(vf1, pf, acc1, 0, 0, 0);
    }
#pragma unroll
    for (int jj = 0; jj < 4; ++jj) { acc0[jj] *= linv_acc; acc1[jj] *= linv_acc; }

    // ---- cross-wave reduce of attn^T, write output ----
    float* ar = attred + (w * 64 + l) * 8;
    *(fx4*)(ar) = acc0;
    *(fx4*)(ar + 4) = acc1;
    BARRIER_LGKM();
    if (w < 2) {
      float s0v = 0.f, s1v = 0.f, s2v = 0.f, s3v = 0.f;
#pragma unroll
      for (int w2 = 0; w2 < 4; ++w2) {
        const float* a2 = attred + (w2 * 64 + l) * 8 + w * 4;
        s0v += a2[0]; s1v += a2[1]; s2v += a2[2]; s3v += a2[3];
      }
      bh4 o = { f2bf(s0v), f2bf(s1v), f2bf(s2v), f2bf(s3v) };
      *(bh4*)(attn_bf + ((size_t)(t0 + lt) * 8 + b) * 1024 + hh * 32 + w * 16 + g * 4) = o;
    }
    // next head's WAIT_VM0_BARRIER protects attred reuse + bias_lds restage
  }

  // ---- head-mean partial writeout: private hg-slab, plain stores ----
  float* mob = mean_part + (size_t)hg * SLAB_ + ((size_t)b * 512 + t0) * 768;
#pragma unroll
  for (int c = 0; c < 12; ++c) {
    const int s = sbase + c * 16 + lt;
#pragma unroll
    for (int jj = 0; jj < 4; ++jj) {
      mob[(size_t)(g * 4 + jj) * 768 + s] = msum[c * 4 + jj] * 0.03125f;
    }
  }
}

// ---- fused: blocks [0,3072) sum 2 hg-slabs; blocks [3072,4096) LayerNorm ----
__global__ __launch_bounds__(256) void mean_ln(
    const float* __restrict__ mean_part, float* __restrict__ mean_out,
    const short* __restrict__ attn_bf, const float* __restrict__ lg,
    const float* __restrict__ lb, short* __restrict__ xhat) {
  if (blockIdx.x < 3072) {
    size_t i = ((size_t)blockIdx.x * 256 + threadIdx.x) * 4;
    fx4 a = *(const fx4*)(mean_part + i);
    fx4 b = *(const fx4*)(mean_part + SLAB_ + i);
#pragma unroll
    for (int k = 0; k < 4; ++k) a[k] = a[k] + b[k];
    *(fx4*)(mean_out + i) = a;
    return;
  }
  const int w = threadIdx.x >> 6, l = threadIdx.x & 63;
  const size_t row = (size_t)(blockIdx.x - 3072) * 4 + w;
  const short* x = attn_bf + row * 1024 + l * 16;
  bh8 a0 = *(const bh8*)x, a1 = *(const bh8*)(x + 8);
  float xs[16];
#pragma unroll
  for (int i = 0; i < 8; ++i) { xs[i] = bf2f(a0[i]); xs[8 + i] = bf2f(a1[i]); }
  float s1 = 0.f, s2 = 0.f;
#pragma unroll
  for (int i = 0; i < 16; ++i) { s1 += xs[i]; s2 += xs[i] * xs[i]; }
  for (int m = 1; m < 64; m <<= 1) { s1 += __shfl_xor(s1, m); s2 += __shfl_xor(s2, m); }
  const float mu = s1 * (1.0f / 1024.0f);
  float var = s2 * (1.0f / 1024.0f) - mu * mu;
  var = fmaxf(var, 0.f);
  const float rs = rsqrtf(var + 1e-5f);
  const float* lgp = lg + l * 16;
  const float* lbp = lb + l * 16;
  bh8 o0, o1;
#pragma unroll
  for (int i = 0; i < 8; ++i) {
    o0[i] = f2bf((xs[i] - mu) * rs * lgp[i] + lbp[i]);
    o1[i] = f2bf((xs[8 + i] - mu) * rs * lgp[8 + i] + lbp[8 + i]);
  }
  short* y = xhat + row * 1024 + l * 16;
  *(bh8*)y = o0;
  *(bh8*)(y + 8) = o1;
}

// ---- output projection GEMM ----
__global__ __launch_bounds__(256) void out_gemm(
    const short* __restrict__ XH, const short* __restrict__ WoB,
    const float* __restrict__ bo, float* __restrict__ out) {
  __shared__ __align__(16) short As[128 * 32];
  __shared__ __align__(16) short Ws[128 * 32];
  const int tid = threadIdx.x;
  const int mt = blockIdx.x, nt = blockIdx.y;
  const size_t m0 = (size_t)mt * 128;
  const int n0 = nt << 7;
  const int l = tid & 63, wv_ = tid >> 6;
  const int lt = l & 15, g = l >> 4;
  const int wm = wv_ >> 1, wn = wv_ & 1;
  fx4 acc[4][4];
#pragma unroll
  for (int i = 0; i < 4; ++i)
#pragma unroll
    for (int j = 0; j < 4; ++j) acc[i][j] = fx4{0.f, 0.f, 0.f, 0.f};
  const int r0 = tid >> 2, c0 = tid & 3;
  for (int kt = 0; kt < 32; ++kt) {
    const int k0 = kt * 32;
    __syncthreads();
    gl_lds16(XH + (m0 + r0) * 1024 + k0 + c0 * 8,        As + r0 * 32 + c0 * 8);
    gl_lds16(XH + (m0 + 64 + r0) * 1024 + k0 + c0 * 8,   As + (64 + r0) * 32 + c0 * 8);
    gl_lds16(WoB + (size_t)(n0 + r0) * 1024 + k0 + c0 * 8,      Ws + r0 * 32 + c0 * 8);
    gl_lds16(WoB + (size_t)(n0 + 64 + r0) * 1024 + k0 + c0 * 8, Ws + (64 + r0) * 32 + c0 * 8);
    __syncthreads();
    bh8 af[4], wf[4];
#pragma unroll
    for (int i = 0; i < 4; ++i) af[i] = *(const bh8*)(As + (wm * 64 + i * 16 + lt) * 32 + g * 8);
#pragma unroll
    for (int j = 0; j < 4; ++j) wf[j] = *(const bh8*)(Ws + (wn * 64 + j * 16 + lt) * 32 + g * 8);
#pragma unroll
    for (int i = 0; i < 4; ++i)
#pragma unroll
      for (int j = 0; j < 4; ++j)
        acc[i][j] = __builtin_amdgcn_mfma_f32_16x16x32_bf16(af[i], wf[j], acc[i][j], 0, 0, 0);
  }
#pragma unroll
  for (int i = 0; i < 4; ++i) {
    const size_t rowb = m0 + wm * 64 + i * 16 + g * 4;
#pragma unroll
    for (int j = 0; j < 4; ++j) {
      const int col = n0 + wn * 64 + j * 16 + lt;
      const float bb = bo[col];
#pragma unroll
      for (int jj = 0; jj < 4; ++jj)
        out[(rowb + jj) * 1024 + col] = acc[i][j][jj] + bb;
    }
  }
}

extern "C" void kernel_launch(void* const* d_in, const int* in_sizes, int n_in,
                              void* d_out, int out_size, void* d_ws, size_t ws_size,
                              hipStream_t stream) {
  const float* query = (const float*)d_in[0];
  const float* attn_bias = (const float*)d_in[1];
  const int* oc = (const int*)d_in[2];
  const unsigned char* em = (const unsigned char*)d_in[3];
  const unsigned char* kp = (const unsigned char*)d_in[4];
  const float* Wq = (const float*)d_in[5];
  const float* bq = (const float*)d_in[6];
  const float* Wk = (const float*)d_in[7];
  const float* Wv = (const float*)d_in[8];
  const float* bv = (const float*)d_in[9];
  const float* Wo = (const float*)d_in[10];
  const float* bo = (const float*)d_in[11];
  const float* lg = (const float*)d_in[12];
  const float* lb = (const float*)d_in[13];

  char* w = (char*)d_ws;
  short* QB    = (short*)(w + OFF_QB);
  short* WB    = (short*)(w + OFF_WB);
  short* QRM   = (short*)(w + OFF_QRM);
  short* KRM   = (short*)(w + OFF_KRM);
  short* VRM   = (short*)(w + OFF_VRM);
  short* KBF   = (short*)(w + OFF_KBF);
  short* VT    = (short*)(w + OFF_VT);
  short* ATTN  = (short*)(w + OFF_ATTN);
  short* XHAT  = (short*)(w + OFF_XHAT);
  float* MASK  = (float*)(w + OFF_MASK);
  int*   FLAG  = (int*)(w + OFF_FLAG);
  float* MEANP = (float*)(w + OFF_MEANP);

  float* out0 = (float*)d_out;                       // [T,B,E]
  float* mean_out = out0 + (size_t)T_ * B_ * E_;     // [B,T,S]

  conv_all<<<8192, 256, 0, stream>>>(query, Wq, Wk, Wv, Wo, QB, WB, em, FLAG);
  qkv_gemm<<<dim3(32, 24), 256, 0, stream>>>(QB, WB, bq, bv, QRM, KRM, VRM);
  repack<<<2328, 256, 0, stream>>>(KRM, VRM, oc, em, kp, FLAG, KBF, VT, MASK);
  attn_kernel<<<512, 256, 0, stream>>>(QRM, KBF, VT, attn_bias, MASK, ATTN, MEANP);
  mean_ln<<<4096, 256, 0, stream>>>(MEANP, mean_out, ATTN, lg, lb, XHAT);
  out_gemm<<<dim3(32, 8), 256, 0, stream>>>(XHAT, WB + (size_t)3 * 1024 * 1024, bo, out0);
}